// Round 1
// 919.709 us; speedup vs baseline: 1.1082x; 1.1082x over previous
//
#include <hip/hip_runtime.h>
#include <hip/hip_bf16.h>
#include <cstdint>

// Problem: out_re = x_re@Re^T - x_im@Im^T ; out_im = x_re@Im^T + x_im@Re^T
// Folded into one GEMM: A = [x_re | x_im]  (M x 1024, fp32 in HBM, bf16 in LDS)
//                       Bt[o][k] = [[Re,-Im],[Im,Re]]  (1024 x 1024, bf16, packed once)
//                       C columns [0,512) -> out_re, [512,1024) -> out_im
// fp32->bf16 conversion is FUSED into GEMM A-staging (no pack_a pass).
#define NROWS  100000
#define KDIM   1024
#define BM     128
#define BN     128
#define BK     64
#define MTILES 782            // ceil(100000/128)
#define NTILES 8
#define NBLK   (MTILES * NTILES)   // 6256, divisible by 8

typedef __attribute__((ext_vector_type(8))) __bf16 bf16x8;
typedef __attribute__((ext_vector_type(4))) float  f32x4;

__device__ __forceinline__ uint16_t f2bf(float f) {
    union { float f; uint32_t u; } v; v.f = f;
    uint32_t u = v.u;
    u += 0x7FFFu + ((u >> 16) & 1u);   // RNE
    return (uint16_t)(u >> 16);
}

// HW packed fp32->bf16 (RNE), 2 values / instruction
__device__ __forceinline__ uint32_t pkbf(float lo, float hi) {
    uint32_t r;
    asm("v_cvt_pk_bf16_f32 %0, %1, %2" : "=v"(r) : "v"(lo), "v"(hi));
    return r;
}

__device__ __forceinline__ void async16(const uint16_t* g, uint16_t* l) {
    // global -> LDS direct copy, 16B per lane (global_load_lds_dwordx4)
    __builtin_amdgcn_global_load_lds(
        (const __attribute__((address_space(1))) uint32_t*)g,
        (__attribute__((address_space(3))) uint32_t*)l,
        16, 0, 0);
}

// ------------- pack Bt: [[Re, -Im],[Im, Re]] row-major (o_c, k) bf16 -------------
__global__ __launch_bounds__(256) void pack_b_kernel(
        const float* __restrict__ Re, const float* __restrict__ Im,
        uint16_t* __restrict__ Bt) {
    int c  = blockIdx.x * 256 + threadIdx.x;  // 8 bf16 per chunk; 128 chunks/row
    int oc = c >> 7;
    int j  = c & 127;
    const float* src;
    float sgn = 1.0f;
    if (oc < 512) {
        if (j < 64) { src = Re + (size_t)oc * 512 + (size_t)j * 8; }
        else        { src = Im + (size_t)oc * 512 + (size_t)(j - 64) * 8; sgn = -1.0f; }
    } else {
        int o = oc - 512;
        if (j < 64) { src = Im + (size_t)o * 512 + (size_t)j * 8; }
        else        { src = Re + (size_t)o * 512 + (size_t)(j - 64) * 8; }
    }
    float4 a = ((const float4*)src)[0];
    float4 b = ((const float4*)src)[1];
    uint32_t p0 = (uint32_t)f2bf(sgn * a.x) | ((uint32_t)f2bf(sgn * a.y) << 16);
    uint32_t p1 = (uint32_t)f2bf(sgn * a.z) | ((uint32_t)f2bf(sgn * a.w) << 16);
    uint32_t p2 = (uint32_t)f2bf(sgn * b.x) | ((uint32_t)f2bf(sgn * b.y) << 16);
    uint32_t p3 = (uint32_t)f2bf(sgn * b.z) | ((uint32_t)f2bf(sgn * b.w) << 16);
    uint4 v; v.x = p0; v.y = p1; v.z = p2; v.w = p3;
    *(uint4*)(Bt + (size_t)c * 8) = v;
}

// --------- fused GEMM: 128x128 tile, BK=64, dbuf LDS, 1 barrier / K-step ---------
// LDS layout (both A and B): granule = 8 bf16 = 16 B; 8 granules per 64-wide row.
// Granule (row,kk) lives at slot row*8 + (kk ^ (row&7))  -> conflict-free b128 reads.
// A: linear global read (fp32) -> v_cvt_pk_bf16 -> ds_write to SWIZZLED slot.
// B: global_load_lds to LINEAR slot, global source address pre-swizzled (m173).
__global__ __launch_bounds__(256) void gemm_fused(
        const float* __restrict__ xre, const float* __restrict__ xim,
        const uint16_t* __restrict__ Bt, float* __restrict__ C) {
    __shared__ uint16_t As[2 * BM * BK];   // 2 x 16 KB
    __shared__ uint16_t Bs[2 * BN * BK];   // 2 x 16 KB

    const int t    = threadIdx.x;
    const int wave = t >> 6;
    const int lane = t & 63;
    const int q    = lane >> 4;            // k-quad: k = q*8 + j
    const int r16  = lane & 15;
    const int wm   = wave >> 1;            // 2x2 waves -> 64x64 each
    const int wn   = wave & 1;

    // XCD-chunked bijective swizzle: 8 colTiles of one rowTile land consecutively
    // on one XCD -> A tile (512 KB fp32) fetched once, then L2-hit.
    const int bid     = blockIdx.x;
    const int newid   = (bid & 7) * (NBLK / 8) + (bid >> 3);
    const int colTile = newid & 7;
    const int rowTile = newid >> 3;

    const int aRow0 = rowTile * BM;
    const int bRow0 = colTile * BN;

    // staging geometry: 4 granules / thread / array / K-step
    int  aLds[4];                 // swizzled LDS element offset for A ds_write
    int  aOff[4];                 // global element offset into xre/xim (k-base added per step)
    bool aOk[4];
    const uint16_t* bPtr[4];      // pre-swizzled global source for B
    int  bLds[4];                 // linear LDS element offset for B
#pragma unroll
    for (int i = 0; i < 4; ++i) {
        int g   = i * 256 + t;
        int row = g >> 3;         // 0..127
        int kk  = g & 7;
        int swz = kk ^ (row & 7);
        aLds[i] = (row * 8 + swz) * 8;
        int grow = aRow0 + row;
        aOk[i]  = grow < NROWS;
        aOff[i] = grow * 512 + kk * 8;
        bPtr[i] = Bt + (size_t)(bRow0 + row) * KDIM + swz * 8;
        bLds[i] = g * 8;
    }

    // fragment LDS element offsets: (mi/ni, k-slice ks) at granule col ks*4+q
    int gra[4][2], grb[4][2];
#pragma unroll
    for (int x = 0; x < 4; ++x) {
#pragma unroll
        for (int ks = 0; ks < 2; ++ks) {
            int rowA = wm * 64 + x * 16 + r16;
            gra[x][ks] = (rowA * 8 + ((ks * 4 + q) ^ (rowA & 7))) * 8;
            int rowB = wn * 64 + x * 16 + r16;
            grb[x][ks] = (rowB * 8 + ((ks * 4 + q) ^ (rowB & 7))) * 8;
        }
    }

    f32x4 acc[4][4] = {};

    // ---- prologue: stage K-step 0 into buffer 0 ----
    {
        float4 va[4], vb[4];
#pragma unroll
        for (int i = 0; i < 4; ++i) {
            if (aOk[i]) {
                const float4* p = (const float4*)(xre + aOff[i]);
                va[i] = p[0]; vb[i] = p[1];
            } else {
                va[i] = make_float4(0.f, 0.f, 0.f, 0.f);
                vb[i] = make_float4(0.f, 0.f, 0.f, 0.f);
            }
        }
#pragma unroll
        for (int i = 0; i < 4; ++i)
            async16(bPtr[i], Bs + bLds[i]);
#pragma unroll
        for (int i = 0; i < 4; ++i) {
            uint4 u;
            u.x = pkbf(va[i].x, va[i].y);
            u.y = pkbf(va[i].z, va[i].w);
            u.z = pkbf(vb[i].x, vb[i].y);
            u.w = pkbf(vb[i].z, vb[i].w);
            *(uint4*)(As + aLds[i]) = u;
        }
        __syncthreads();   // drains vmcnt (async16) + lgkmcnt (ds_write)
    }

    int cur = 0;
    for (int kt = 0; kt < 16; ++kt) {
        const int nxt = cur ^ 1;

        // ---- issue next-step staging FIRST (hides under MFMA) ----
        float4 va[4], vb[4];
        if (kt < 15) {
            const float* src = (kt + 1 < 8) ? xre : xim;   // K-step never straddles 512
            const int kb = ((kt + 1) & 7) * 64;
#pragma unroll
            for (int i = 0; i < 4; ++i) {
                if (aOk[i]) {
                    const float4* p = (const float4*)(src + aOff[i] + kb);
                    va[i] = p[0]; vb[i] = p[1];
                } else {
                    va[i] = make_float4(0.f, 0.f, 0.f, 0.f);
                    vb[i] = make_float4(0.f, 0.f, 0.f, 0.f);
                }
            }
            const size_t gk = (size_t)(kt + 1) * 64;
#pragma unroll
            for (int i = 0; i < 4; ++i)
                async16(bPtr[i] + gk, Bs + nxt * (BN * BK) + bLds[i]);
        }

        // ---- compute on buffer cur ----
        const uint16_t* Ab = As + cur * (BM * BK);
        const uint16_t* Bb = Bs + cur * (BN * BK);
        bf16x8 af[4][2], bfr[4][2];
#pragma unroll
        for (int x = 0; x < 4; ++x) {
#pragma unroll
            for (int ks = 0; ks < 2; ++ks) {
                af[x][ks]  = *(const bf16x8*)(Ab + gra[x][ks]);
                bfr[x][ks] = *(const bf16x8*)(Bb + grb[x][ks]);
            }
        }
#pragma unroll
        for (int mi = 0; mi < 4; ++mi)
#pragma unroll
            for (int ni = 0; ni < 4; ++ni) {
                acc[mi][ni] = __builtin_amdgcn_mfma_f32_16x16x32_bf16(
                    af[mi][0], bfr[ni][0], acc[mi][ni], 0, 0, 0);
                acc[mi][ni] = __builtin_amdgcn_mfma_f32_16x16x32_bf16(
                    af[mi][1], bfr[ni][1], acc[mi][ni], 0, 0, 0);
            }

        // ---- convert + publish A for next step (after MFMA; vmcnt auto-waited) ----
        if (kt < 15) {
            uint16_t* Ad = As + nxt * (BM * BK);
#pragma unroll
            for (int i = 0; i < 4; ++i) {
                uint4 u;
                u.x = pkbf(va[i].x, va[i].y);
                u.y = pkbf(va[i].z, va[i].w);
                u.z = pkbf(vb[i].x, vb[i].y);
                u.w = pkbf(vb[i].z, vb[i].w);
                *(uint4*)(Ad + aLds[i]) = u;
            }
        }
        __syncthreads();   // single barrier per K-step publishes both A and B
        cur = nxt;
    }

    // epilogue: C/D layout col = lane&15, row = q*4 + reg  (m89/m91 verified)
    const size_t outHalf = (colTile < 4) ? 0 : (size_t)NROWS * 512;
    const int cbase = (colTile & 3) * 128 + wn * 64;
#pragma unroll
    for (int mi = 0; mi < 4; ++mi) {
        int rbase = aRow0 + wm * 64 + mi * 16 + q * 4;
#pragma unroll
        for (int ni = 0; ni < 4; ++ni) {
            int col = cbase + ni * 16 + r16;
#pragma unroll
            for (int r = 0; r < 4; ++r) {
                int row = rbase + r;
                if (row < NROWS)
                    C[outHalf + (size_t)row * 512 + col] = acc[mi][ni][r];
            }
        }
    }
}

// ---------------- fp32 fallback (only if ws too small for Bt) ----------------
__global__ void fallback_kernel(const float* __restrict__ xre,
                                const float* __restrict__ xim,
                                const float* __restrict__ Re,
                                const float* __restrict__ Im,
                                float* __restrict__ out) {
    __shared__ float sre[512], sim[512];
    int n = blockIdx.x;
    for (int i = threadIdx.x; i < 512; i += 256) {
        sre[i] = xre[(size_t)n * 512 + i];
        sim[i] = xim[(size_t)n * 512 + i];
    }
    __syncthreads();
    for (int o = threadIdx.x; o < 512; o += 256) {
        float are = 0.f, aim = 0.f;
        for (int k = 0; k < 512; ++k) {
            float wr = Re[(size_t)o * 512 + k], wi = Im[(size_t)o * 512 + k];
            float xr = sre[k], xi = sim[k];
            are += xr * wr - xi * wi;
            aim += xr * wi + xi * wr;
        }
        out[(size_t)n * 512 + o] = are;
        out[(size_t)NROWS * 512 + (size_t)n * 512 + o] = aim;
    }
}

extern "C" void kernel_launch(void* const* d_in, const int* in_sizes, int n_in,
                              void* d_out, int out_size, void* d_ws, size_t ws_size,
                              hipStream_t stream) {
    const float* xre = (const float*)d_in[0];
    const float* xim = (const float*)d_in[1];
    const float* Re  = (const float*)d_in[2];
    const float* Im  = (const float*)d_in[3];
    float* out = (float*)d_out;

    const size_t bBytes = (size_t)1024 * KDIM * 2;   // 2 MiB packed weights
    if (ws_size >= bBytes) {
        uint16_t* Bt = (uint16_t*)d_ws;
        pack_b_kernel<<<(1024 * 128) / 256, 256, 0, stream>>>(Re, Im, Bt);
        gemm_fused<<<NBLK, 256, 0, stream>>>(xre, xim, Bt, out);
    } else {
        fallback_kernel<<<NROWS, 256, 0, stream>>>(xre, xim, Re, Im, out);
    }
}

// Round 2
// 867.315 us; speedup vs baseline: 1.1751x; 1.0604x over previous
//
#include <hip/hip_runtime.h>
#include <hip/hip_bf16.h>
#include <cstdint>

// Problem: out_re = x_re@Re^T - x_im@Im^T ; out_im = x_re@Im^T + x_im@Re^T
// One GEMM: A = [x_re | x_im] (MPAD x 1024 bf16, packed), Bt = [[Re,-Im],[Im,Re]]
// (1024 x 1024 bf16). C cols [0,512)->out_re, [512,1024)->out_im.
// GEMM = 256x256-tile 8-phase schedule (T1+T2+T3+T4+T5 per catalog):
//   8 waves (2Mx4N), BK=64, 128 KB LDS dbuf, 2 barriers/phase, 16-MFMA clusters
//   with s_setprio, counted s_waitcnt vmcnt(8) once per K-tile (never 0 in loop).
#define NROWS  100000
#define KDIM   1024
#define MPAD   100096      // 391*256
#define MTILES 391
#define NTILES 4
#define NBLK   (MTILES * NTILES)   // 1564

typedef __attribute__((ext_vector_type(8))) __bf16 bf16x8;
typedef __attribute__((ext_vector_type(4))) float  f32x4;

__device__ __forceinline__ uint16_t f2bf(float f) {
    union { float f; uint32_t u; } v; v.f = f;
    uint32_t u = v.u;
    u += 0x7FFFu + ((u >> 16) & 1u);   // RNE
    return (uint16_t)(u >> 16);
}

__device__ __forceinline__ void async16(const uint16_t* g, uint16_t* l) {
    // global -> LDS direct copy, 16B per lane (global_load_lds_dwordx4)
    __builtin_amdgcn_global_load_lds(
        (const __attribute__((address_space(1))) uint32_t*)g,
        (__attribute__((address_space(3))) uint32_t*)l,
        16, 0, 0);
}

// ---------------- pack A: [x_re | x_im] -> bf16, zero pad rows ----------------
__global__ __launch_bounds__(256) void pack_a_kernel(
        const float* __restrict__ xre, const float* __restrict__ xim,
        uint16_t* __restrict__ A) {
    int c = blockIdx.x * 256 + threadIdx.x;   // 16B chunk (8 bf16); 128 chunks/row
    int n = c >> 7;
    int j = c & 127;                          // wave-uniform re/im split
    uint32_t p0 = 0, p1 = 0, p2 = 0, p3 = 0;
    if (n < NROWS) {
        const float* src = (j < 64) ? (xre + (size_t)n * 512 + (size_t)j * 8)
                                    : (xim + (size_t)n * 512 + (size_t)(j - 64) * 8);
        float4 a = ((const float4*)src)[0];
        float4 b = ((const float4*)src)[1];
        p0 = (uint32_t)f2bf(a.x) | ((uint32_t)f2bf(a.y) << 16);
        p1 = (uint32_t)f2bf(a.z) | ((uint32_t)f2bf(a.w) << 16);
        p2 = (uint32_t)f2bf(b.x) | ((uint32_t)f2bf(b.y) << 16);
        p3 = (uint32_t)f2bf(b.z) | ((uint32_t)f2bf(b.w) << 16);
    }
    uint4 v; v.x = p0; v.y = p1; v.z = p2; v.w = p3;
    *(uint4*)(A + (size_t)c * 8) = v;
}

// ------------- pack Bt: [[Re, -Im],[Im, Re]] row-major (o_c, k) bf16 -------------
__global__ __launch_bounds__(256) void pack_b_kernel(
        const float* __restrict__ Re, const float* __restrict__ Im,
        uint16_t* __restrict__ Bt) {
    int c  = blockIdx.x * 256 + threadIdx.x;
    int oc = c >> 7;
    int j  = c & 127;
    const float* src;
    float sgn = 1.0f;
    if (oc < 512) {
        if (j < 64) { src = Re + (size_t)oc * 512 + (size_t)j * 8; }
        else        { src = Im + (size_t)oc * 512 + (size_t)(j - 64) * 8; sgn = -1.0f; }
    } else {
        int o = oc - 512;
        if (j < 64) { src = Im + (size_t)o * 512 + (size_t)j * 8; }
        else        { src = Re + (size_t)o * 512 + (size_t)(j - 64) * 8; }
    }
    float4 a = ((const float4*)src)[0];
    float4 b = ((const float4*)src)[1];
    uint32_t p0 = (uint32_t)f2bf(sgn * a.x) | ((uint32_t)f2bf(sgn * a.y) << 16);
    uint32_t p1 = (uint32_t)f2bf(sgn * a.z) | ((uint32_t)f2bf(sgn * a.w) << 16);
    uint32_t p2 = (uint32_t)f2bf(sgn * b.x) | ((uint32_t)f2bf(sgn * b.y) << 16);
    uint32_t p3 = (uint32_t)f2bf(sgn * b.z) | ((uint32_t)f2bf(sgn * b.w) << 16);
    uint4 v; v.x = p0; v.y = p1; v.z = p2; v.w = p3;
    *(uint4*)(Bt + (size_t)c * 8) = v;
}

// ---------------- 256x256 8-phase GEMM ----------------
// LDS: 2 bufs x [A 256x64 | B 256x64] bf16 = 2 x 64 KB. Granule (=8 bf16 = 16B)
// swizzle within each 128x64 half: slot(row,kk) = row*8 + (kk ^ (row&7))
// (proven 0-conflict in prior round). Staging via global_load_lds to LINEAR slots
// with pre-swizzled global source (m173).
// Phases per K-tile (wave wm owns A-half wm; quadrants Q(miH,niH)):
//  P1: ds_read A(miH=0) 8 + B(niH=0) 4 | bar | 16 MFMA Q(0,0) | bar
//  P2: ds_read B(niH=1) 4              | bar | 16 MFMA Q(0,1) | bar
//  P3: ds_read A(miH=1) 8; issue B-stage(kt+2) | bar | 16 MFMA Q(1,1) | bar
//  P4: issue A-stage(kt+2) | bar | 16 MFMA Q(1,0) | vmcnt(8) | bar
// Region safety: B regions dead after P2-end barrier (P4 uses b0 from regs),
// A regions dead after P3-end barrier; restage happens strictly after.
// Residency: per-wave vmcnt(8) leaves only tile kt+2's 8 loads outstanding ->
// tile kt+1 fully written before any wave crosses the P4-end barrier.
__global__ __launch_bounds__(512, 2) void gemm8(
        const uint16_t* __restrict__ A, const uint16_t* __restrict__ Bt,
        float* __restrict__ C) {
    __shared__ uint16_t lds[65536];   // 128 KB

    const int t    = threadIdx.x;
    const int wave = t >> 6;
    const int lane = t & 63;
    const int q    = lane >> 4;        // k-quad: k = q*8 + j
    const int r16  = lane & 15;
    const int wm   = wave >> 2;        // 0..1  (A-half owner)
    const int wn   = wave & 3;         // 0..3

    // bijective XCD-chunk swizzle (m204): nwg=1564, q8=195, r8=4
    const int bid  = blockIdx.x;
    const int xcd  = bid & 7, lid = bid >> 3;
    const int wgid = (xcd < 4 ? xcd * 196 : 784 + (xcd - 4) * 195) + lid;
    const int colTile = wgid & 3;      // fastest -> A-panel L2 reuse within XCD
    const int rowTile = wgid >> 2;
    const int aRow0   = rowTile * 256;

    // fragment ds_read sub-offsets (swizzle dep only on r16&7; +16/+64 rows keep it)
    const int s7  = r16 & 7;
    const int sA0 = r16 * 64 + ((q ^ s7) << 3);
    const int sA1 = r16 * 64 + (((q + 4) ^ s7) << 3);

    // staging geometry: per thread 2 granules per half-tile
    const int g0 = t, g1 = t + 512;
    const int r0 = g0 >> 3, k0 = ((g0 & 7) ^ (r0 & 7)) << 3;
    const int r1 = g1 >> 3, k1 = ((g1 & 7) ^ (r1 & 7)) << 3;
    const int lA00 = g0 * 8,          lA01 = g1 * 8;           // A half0
    const int lA10 = 8192 + g0 * 8,   lA11 = 8192 + g1 * 8;    // A half1
    const int lB00 = 16384 + g0 * 8,  lB01 = 16384 + g1 * 8;   // B half0
    const int lB10 = 24576 + g0 * 8,  lB11 = 24576 + g1 * 8;   // B half1
    const uint16_t* pA00 = A  + (size_t)(aRow0 + r0) * KDIM + k0;
    const uint16_t* pA01 = A  + (size_t)(aRow0 + r1) * KDIM + k1;
    const uint16_t* pA10 = A  + (size_t)(aRow0 + 128 + r0) * KDIM + k0;
    const uint16_t* pA11 = A  + (size_t)(aRow0 + 128 + r1) * KDIM + k1;
    const uint16_t* pB00 = Bt + (size_t)(colTile * 256 + r0) * KDIM + k0;
    const uint16_t* pB01 = Bt + (size_t)(colTile * 256 + r1) * KDIM + k1;
    const uint16_t* pB10 = Bt + (size_t)(colTile * 256 + 128 + r0) * KDIM + k0;
    const uint16_t* pB11 = Bt + (size_t)(colTile * 256 + 128 + r1) * KDIM + k1;

    // ---- prologue: tile0 -> buf0, tile1 -> buf1; wait tile0 (vmcnt leaves 8) ----
    async16(pA00, lds + lA00); async16(pA01, lds + lA01);
    async16(pA10, lds + lA10); async16(pA11, lds + lA11);
    async16(pB00, lds + lB00); async16(pB01, lds + lB01);
    async16(pB10, lds + lB10); async16(pB11, lds + lB11);
    async16(pA00 + 64, lds + 32768 + lA00); async16(pA01 + 64, lds + 32768 + lA01);
    async16(pA10 + 64, lds + 32768 + lA10); async16(pA11 + 64, lds + 32768 + lA11);
    async16(pB00 + 64, lds + 32768 + lB00); async16(pB01 + 64, lds + 32768 + lB01);
    async16(pB10 + 64, lds + 32768 + lB10); async16(pB11 + 64, lds + 32768 + lB11);
    pA00 += 128; pA01 += 128; pA10 += 128; pA11 += 128;
    pB00 += 128; pB01 += 128; pB10 += 128; pB11 += 128;
    asm volatile("s_waitcnt vmcnt(8)" ::: "memory");
    __builtin_amdgcn_s_barrier();

    f32x4 acc[8][4] = {};

#pragma unroll 2
    for (int kt = 0; kt < 16; ++kt) {
        const int bufO = (kt & 1) << 15;
        const uint16_t* bA = lds + bufO + wm * 8192;
        const uint16_t* bB = lds + bufO + 16384 + (wn >> 1) * 8192 + (wn & 1) * 4096;
        uint16_t* ldsd = lds + bufO;     // restage target = current buf (tile kt+2)

        bf16x8 af[4][2], b0[2][2], b1[2][2];
        // -------- P1 --------
#pragma unroll
        for (int mi = 0; mi < 4; ++mi) {
            af[mi][0] = *(const bf16x8*)(bA + mi * 1024 + sA0);
            af[mi][1] = *(const bf16x8*)(bA + mi * 1024 + sA1);
        }
#pragma unroll
        for (int ni = 0; ni < 2; ++ni) {
            b0[ni][0] = *(const bf16x8*)(bB + ni * 1024 + sA0);
            b0[ni][1] = *(const bf16x8*)(bB + ni * 1024 + sA1);
        }
        __builtin_amdgcn_s_barrier();
        __builtin_amdgcn_s_setprio(1);
#pragma unroll
        for (int mi = 0; mi < 4; ++mi)
#pragma unroll
            for (int nj = 0; nj < 2; ++nj) {
                acc[mi][nj] = __builtin_amdgcn_mfma_f32_16x16x32_bf16(af[mi][0], b0[nj][0], acc[mi][nj], 0, 0, 0);
                acc[mi][nj] = __builtin_amdgcn_mfma_f32_16x16x32_bf16(af[mi][1], b0[nj][1], acc[mi][nj], 0, 0, 0);
            }
        __builtin_amdgcn_s_setprio(0);
        __builtin_amdgcn_s_barrier();
        // -------- P2 --------
#pragma unroll
        for (int ni = 0; ni < 2; ++ni) {
            b1[ni][0] = *(const bf16x8*)(bB + 2048 + ni * 1024 + sA0);
            b1[ni][1] = *(const bf16x8*)(bB + 2048 + ni * 1024 + sA1);
        }
        __builtin_amdgcn_s_barrier();
        __builtin_amdgcn_s_setprio(1);
#pragma unroll
        for (int mi = 0; mi < 4; ++mi)
#pragma unroll
            for (int nj = 0; nj < 2; ++nj) {
                acc[mi][2 + nj] = __builtin_amdgcn_mfma_f32_16x16x32_bf16(af[mi][0], b1[nj][0], acc[mi][2 + nj], 0, 0, 0);
                acc[mi][2 + nj] = __builtin_amdgcn_mfma_f32_16x16x32_bf16(af[mi][1], b1[nj][1], acc[mi][2 + nj], 0, 0, 0);
            }
        __builtin_amdgcn_s_setprio(0);
        __builtin_amdgcn_s_barrier();
        // -------- P3 --------
#pragma unroll
        for (int mi = 0; mi < 4; ++mi) {
            af[mi][0] = *(const bf16x8*)(bA + 4096 + mi * 1024 + sA0);
            af[mi][1] = *(const bf16x8*)(bA + 4096 + mi * 1024 + sA1);
        }
        if (kt < 14) {   // B regions of this buf dead since P2-end barrier
            __builtin_amdgcn_sched_barrier(0);
            async16(pB00, ldsd + lB00); async16(pB01, ldsd + lB01);
            async16(pB10, ldsd + lB10); async16(pB11, ldsd + lB11);
        }
        __builtin_amdgcn_s_barrier();
        __builtin_amdgcn_s_setprio(1);
#pragma unroll
        for (int mi = 0; mi < 4; ++mi)
#pragma unroll
            for (int nj = 0; nj < 2; ++nj) {
                acc[4 + mi][2 + nj] = __builtin_amdgcn_mfma_f32_16x16x32_bf16(af[mi][0], b1[nj][0], acc[4 + mi][2 + nj], 0, 0, 0);
                acc[4 + mi][2 + nj] = __builtin_amdgcn_mfma_f32_16x16x32_bf16(af[mi][1], b1[nj][1], acc[4 + mi][2 + nj], 0, 0, 0);
            }
        __builtin_amdgcn_s_setprio(0);
        __builtin_amdgcn_s_barrier();
        // -------- P4 --------
        if (kt < 14) {   // A regions of this buf dead since P3-end barrier
            __builtin_amdgcn_sched_barrier(0);
            async16(pA00, ldsd + lA00); async16(pA01, ldsd + lA01);
            async16(pA10, ldsd + lA10); async16(pA11, ldsd + lA11);
            pA00 += 64; pA01 += 64; pA10 += 64; pA11 += 64;
            pB00 += 64; pB01 += 64; pB10 += 64; pB11 += 64;
        }
        __builtin_amdgcn_s_barrier();
        __builtin_amdgcn_s_setprio(1);
#pragma unroll
        for (int mi = 0; mi < 4; ++mi)
#pragma unroll
            for (int nj = 0; nj < 2; ++nj) {
                acc[4 + mi][nj] = __builtin_amdgcn_mfma_f32_16x16x32_bf16(af[mi][0], b0[nj][0], acc[4 + mi][nj], 0, 0, 0);
                acc[4 + mi][nj] = __builtin_amdgcn_mfma_f32_16x16x32_bf16(af[mi][1], b0[nj][1], acc[4 + mi][nj], 0, 0, 0);
            }
        __builtin_amdgcn_s_setprio(0);
        // counted wait: tile kt+1 resident; only tile kt+2's 8 loads may remain
        if (kt < 14)       asm volatile("s_waitcnt vmcnt(8)" ::: "memory");
        else if (kt == 14) asm volatile("s_waitcnt vmcnt(0)" ::: "memory");
        __builtin_amdgcn_s_barrier();
    }

    // epilogue: C/D layout col = lane&15, row = q*4 + reg (m89/m91 verified)
    const size_t outHalf = (colTile >= 2) ? (size_t)NROWS * 512 : 0;
    const int cb = (colTile & 1) * 256 + wn * 64;
#pragma unroll
    for (int mi8 = 0; mi8 < 8; ++mi8) {
        int rbase = aRow0 + wm * 128 + mi8 * 16 + q * 4;
#pragma unroll
        for (int nj = 0; nj < 4; ++nj) {
            int col = cb + nj * 16 + r16;
#pragma unroll
            for (int r = 0; r < 4; ++r) {
                int row = rbase + r;
                if (row < NROWS)
                    C[outHalf + (size_t)row * 512 + col] = acc[mi8][nj][r];
            }
        }
    }
}

// ---------------- fp32 fallback (only if ws too small) ----------------
__global__ void fallback_kernel(const float* __restrict__ xre,
                                const float* __restrict__ xim,
                                const float* __restrict__ Re,
                                const float* __restrict__ Im,
                                float* __restrict__ out) {
    __shared__ float sre[512], sim[512];
    int n = blockIdx.x;
    for (int i = threadIdx.x; i < 512; i += 256) {
        sre[i] = xre[(size_t)n * 512 + i];
        sim[i] = xim[(size_t)n * 512 + i];
    }
    __syncthreads();
    for (int o = threadIdx.x; o < 512; o += 256) {
        float are = 0.f, aim = 0.f;
        for (int k = 0; k < 512; ++k) {
            float wr = Re[(size_t)o * 512 + k], wi = Im[(size_t)o * 512 + k];
            float xr = sre[k], xi = sim[k];
            are += xr * wr - xi * wi;
            aim += xr * wi + xi * wr;
        }
        out[(size_t)n * 512 + o] = are;
        out[(size_t)NROWS * 512 + (size_t)n * 512 + o] = aim;
    }
}

extern "C" void kernel_launch(void* const* d_in, const int* in_sizes, int n_in,
                              void* d_out, int out_size, void* d_ws, size_t ws_size,
                              hipStream_t stream) {
    const float* xre = (const float*)d_in[0];
    const float* xim = (const float*)d_in[1];
    const float* Re  = (const float*)d_in[2];
    const float* Im  = (const float*)d_in[3];
    float* out = (float*)d_out;

    const size_t aBytes = (size_t)MPAD * KDIM * 2;   // 204,996,608
    const size_t bBytes = (size_t)1024 * KDIM * 2;   // 2 MiB
    if (ws_size >= aBytes + bBytes) {
        uint16_t* A  = (uint16_t*)d_ws;
        uint16_t* Bt = (uint16_t*)((char*)d_ws + aBytes);
        pack_a_kernel<<<(MPAD * 128) / 256, 256, 0, stream>>>(xre, xim, A);
        pack_b_kernel<<<(1024 * 128) / 256, 256, 0, stream>>>(Re, Im, Bt);
        gemm8<<<NBLK, 512, 0, stream>>>(A, Bt, out);
    } else {
        fallback_kernel<<<NROWS, 256, 0, stream>>>(xre, xim, Re, Im, out);
    }
}

// Round 3
// 816.441 us; speedup vs baseline: 1.2484x; 1.0623x over previous
//
#include <hip/hip_runtime.h>
#include <hip/hip_bf16.h>
#include <cstdint>

// Problem: out_re = x_re@Re^T - x_im@Im^T ; out_im = x_re@Im^T + x_im@Re^T
// One GEMM: A = [x_re | x_im] (M x 1024, fp32 in HBM, bf16 in LDS — conversion
// FUSED into GEMM staging, no pack_a pass), Bt = [[Re,-Im],[Im,Re]] (1024x1024
// bf16, packed once, 2 MiB). C cols [0,512)->out_re, [512,1024)->out_im.
// GEMM: 256x256 tile, BK=64, 8 waves (2Mx4N), 128 KB LDS dbuf, 4 phases/K-tile
// decomposed as (row-half x k-slice) to minimize fragment liveness:
//   Ph1=(h0,ks0) Ph2=(h1,ks0) Ph3=(h1,ks1) Ph4=(h0,ks1), 16 MFMA each.
// A staging: fp32 reg-load (2 phases early) -> v_cvt_pk_bf16_f32 -> ds_write
// into the dead buffer. B staging: global_load_lds, pre-swizzled source.
// Counted waits: compiler's in-order vmcnt before each cvt covers older B
// asyncs transitively; vmcnt never drains to 0 in the main loop.
#define NROWS  100000
#define KDIM   1024
#define MTILES 391         // ceil(100000/256)
#define NTILES 4
#define NBLK   (MTILES * NTILES)   // 1564

typedef __attribute__((ext_vector_type(8))) __bf16 bf16x8;
typedef __attribute__((ext_vector_type(4))) float  f32x4;

__device__ __forceinline__ uint16_t f2bf(float f) {
    union { float f; uint32_t u; } v; v.f = f;
    uint32_t u = v.u;
    u += 0x7FFFu + ((u >> 16) & 1u);   // RNE
    return (uint16_t)(u >> 16);
}

// HW packed fp32->bf16 (RNE), 2 values / instruction
__device__ __forceinline__ uint32_t pkbf(float lo, float hi) {
    uint32_t r;
    asm("v_cvt_pk_bf16_f32 %0, %1, %2" : "=v"(r) : "v"(lo), "v"(hi));
    return r;
}

__device__ __forceinline__ void async16(const uint16_t* g, uint16_t* l) {
    __builtin_amdgcn_global_load_lds(
        (const __attribute__((address_space(1))) uint32_t*)g,
        (__attribute__((address_space(3))) uint32_t*)l,
        16, 0, 0);
}

__device__ __forceinline__ void ldA(const float* p, bool ok, float4& a, float4& b) {
    if (ok) { a = ((const float4*)p)[0]; b = ((const float4*)p)[1]; }
    else    { a = make_float4(0.f,0.f,0.f,0.f); b = make_float4(0.f,0.f,0.f,0.f); }
}

__device__ __forceinline__ void wrA(uint16_t* d, float4 a, float4 b) {
    uint4 u;
    u.x = pkbf(a.x, a.y); u.y = pkbf(a.z, a.w);
    u.z = pkbf(b.x, b.y); u.w = pkbf(b.z, b.w);
    *(uint4*)d = u;
}

// ------------- pack Bt: [[Re, -Im],[Im, Re]] row-major (o_c, k) bf16 -------------
__global__ __launch_bounds__(256) void pack_b_kernel(
        const float* __restrict__ Re, const float* __restrict__ Im,
        uint16_t* __restrict__ Bt) {
    int c  = blockIdx.x * 256 + threadIdx.x;
    int oc = c >> 7;
    int j  = c & 127;
    const float* src;
    float sgn = 1.0f;
    if (oc < 512) {
        if (j < 64) { src = Re + (size_t)oc * 512 + (size_t)j * 8; }
        else        { src = Im + (size_t)oc * 512 + (size_t)(j - 64) * 8; sgn = -1.0f; }
    } else {
        int o = oc - 512;
        if (j < 64) { src = Im + (size_t)o * 512 + (size_t)j * 8; }
        else        { src = Re + (size_t)o * 512 + (size_t)(j - 64) * 8; }
    }
    float4 a = ((const float4*)src)[0];
    float4 b = ((const float4*)src)[1];
    uint32_t p0 = (uint32_t)f2bf(sgn * a.x) | ((uint32_t)f2bf(sgn * a.y) << 16);
    uint32_t p1 = (uint32_t)f2bf(sgn * a.z) | ((uint32_t)f2bf(sgn * a.w) << 16);
    uint32_t p2 = (uint32_t)f2bf(sgn * b.x) | ((uint32_t)f2bf(sgn * b.y) << 16);
    uint32_t p3 = (uint32_t)f2bf(sgn * b.z) | ((uint32_t)f2bf(sgn * b.w) << 16);
    uint4 v; v.x = p0; v.y = p1; v.z = p2; v.w = p3;
    *(uint4*)(Bt + (size_t)c * 8) = v;
}

// ---------------- fused 256x256 8-phase GEMM ----------------
// LDS buf (32768 elem = 64 KB): A [0,16384) (256 rows x 8 granules swizzled),
// B [16384,32768). Granule (row,kk) at slot row*8 + (kk ^ (row&7)).
__global__ __launch_bounds__(512, 2) void gemm8(
        const float* __restrict__ xre, const float* __restrict__ xim,
        const uint16_t* __restrict__ Bt, float* __restrict__ C) {
    __shared__ uint16_t lds[65536];   // 128 KB

    const int t    = threadIdx.x;
    const int wave = t >> 6;
    const int lane = t & 63;
    const int q    = lane >> 4;
    const int r16  = lane & 15;
    const int wm   = wave >> 2;        // 0..1 row-half owner
    const int wn   = wave & 3;         // 0..3

    // bijective XCD-chunk swizzle: nwg=1564 = 8*195 + 4
    const int bid  = blockIdx.x;
    const int xcd  = bid & 7, lid = bid >> 3;
    const int wgid = (xcd < 4 ? xcd * 196 : 784 + (xcd - 4) * 195) + lid;
    const int colTile = wgid & 3;      // fastest -> A-panel L2 reuse within XCD
    const int rowTile = wgid >> 2;
    const int aRow0   = rowTile * 256;

    // fragment ds_read sub-offsets (ks0: granules q, ks1: granules q+4)
    const int s7  = r16 & 7;
    const int sA0 = r16 * 64 + ((q ^ s7) << 3);
    const int sA1 = r16 * 64 + (((q + 4) ^ s7) << 3);

    // staging geometry: thread t covers granule g in row g>>3, swizzled col
    const int r0 = t >> 3;
    const int kc = ((t & 7) ^ (r0 & 7)) << 3;     // fp32/bf16 col offset (elems)
    // A LDS dest slots (linear slot == swizzled granule layout)
    const int lA0 = t * 8;               // rows   0- 63
    const int lA1 = 4096 + t * 8;        // rows  64-127
    const int lA2 = 8192 + t * 8;        // rows 128-191
    const int lA3 = 12288 + t * 8;       // rows 192-255
    // A global element offsets (into xre/xim, 512-wide)
    const size_t base = (size_t)(aRow0 + r0) * 512 + kc;
    const size_t off0 = base;
    const size_t off1 = base + (size_t)64  * 512;
    const size_t off2 = base + (size_t)128 * 512;
    const size_t off3 = base + (size_t)192 * 512;
    const bool ok0 = aRow0 + r0       < NROWS;
    const bool ok1 = aRow0 + 64 + r0  < NROWS;
    const bool ok2 = aRow0 + 128 + r0 < NROWS;
    const bool ok3 = aRow0 + 192 + r0 < NROWS;
    // B: pre-swizzled global sources -> linear LDS slots
    const int lB0 = 16384 + t * 8, lB1 = 20480 + t * 8;
    const int lB2 = 24576 + t * 8, lB3 = 28672 + t * 8;
    const uint16_t* pB0 = Bt + (size_t)(colTile * 256 + r0)       * KDIM + kc;
    const uint16_t* pB1 = Bt + (size_t)(colTile * 256 + 64 + r0)  * KDIM + kc;
    const uint16_t* pB2 = Bt + (size_t)(colTile * 256 + 128 + r0) * KDIM + kc;
    const uint16_t* pB3 = Bt + (size_t)(colTile * 256 + 192 + r0) * KDIM + kc;

    // ---- prologue: A(0) via reg path -> buf0; B(0)->buf0, B(1)->buf1 ----
    {
        float4 a0, b0, a1, b1;
        ldA(xre + off0, ok0, a0, b0);
        ldA(xre + off2, ok2, a1, b1);
        async16(pB0, lds + lB0); async16(pB1, lds + lB1);
        async16(pB2, lds + lB2); async16(pB3, lds + lB3);
        async16(pB0 + 64, lds + 32768 + lB0); async16(pB1 + 64, lds + 32768 + lB1);
        async16(pB2 + 64, lds + 32768 + lB2); async16(pB3 + 64, lds + 32768 + lB3);
        wrA(lds + lA0, a0, b0); wrA(lds + lA2, a1, b1);
        ldA(xre + off1, ok1, a0, b0);
        ldA(xre + off3, ok3, a1, b1);
        wrA(lds + lA1, a0, b0); wrA(lds + lA3, a1, b1);   // full vmcnt drain here (once)
        asm volatile("s_waitcnt lgkmcnt(0)" ::: "memory");
        __builtin_amdgcn_s_barrier();
    }

    f32x4 acc[8][4] = {};
    float4 x0a, x0b, x1a, x1b;          // 16-reg staging block, reused all tiles

#pragma unroll 2
    for (int kt = 0; kt < 16; ++kt) {
        const int bufO = (kt & 1) << 15;
        const uint16_t* bA = lds + bufO + wm * 8192;
        const uint16_t* bB = lds + bufO + 16384 + wn * 4096;
        uint16_t* AdC = lds + bufO;                    // current buf A base
        uint16_t* AdN = lds + (bufO ^ 32768);          // next buf A base
        const float* srcN = (kt + 1 < 8) ? xre : xim;
        const float* spN  = srcN + ((kt + 1) & 7) * 64;

        bf16x8 af[4], bfr[4];
        // ---------------- Ph1: (h0, ks0) ----------------
        if (kt > 0) {   // publish A(kt) rows 64-127/192-255 (read at Ph2/Ph3)
            wrA(AdC + lA1, x0a, x0b); wrA(AdC + lA3, x1a, x1b);
        }
        if (kt < 15) {  // issue A(kt+1) rows 0-63/128-191
            ldA(spN + off0, ok0, x0a, x0b);
            ldA(spN + off2, ok2, x1a, x1b);
            __builtin_amdgcn_sched_barrier(0);
        }
#pragma unroll
        for (int mi = 0; mi < 4; ++mi)
            af[mi] = *(const bf16x8*)(bA + mi * 1024 + sA0);
#pragma unroll
        for (int nj = 0; nj < 4; ++nj)
            bfr[nj] = *(const bf16x8*)(bB + nj * 1024 + sA0);
        asm volatile("s_waitcnt lgkmcnt(0)" ::: "memory");
        __builtin_amdgcn_s_barrier();
        __builtin_amdgcn_s_setprio(1);
#pragma unroll
        for (int mi = 0; mi < 4; ++mi)
#pragma unroll
            for (int nj = 0; nj < 4; ++nj)
                acc[mi][nj] = __builtin_amdgcn_mfma_f32_16x16x32_bf16(
                    af[mi], bfr[nj], acc[mi][nj], 0, 0, 0);
        __builtin_amdgcn_s_setprio(0);
        __builtin_amdgcn_s_barrier();
        // ---------------- Ph2: (h1, ks0) ----------------
#pragma unroll
        for (int mi = 0; mi < 4; ++mi)
            af[mi] = *(const bf16x8*)(bA + 4096 + mi * 1024 + sA0);
        __builtin_amdgcn_s_barrier();
        __builtin_amdgcn_s_setprio(1);
#pragma unroll
        for (int mi = 0; mi < 4; ++mi)
#pragma unroll
            for (int nj = 0; nj < 4; ++nj)
                acc[4 + mi][nj] = __builtin_amdgcn_mfma_f32_16x16x32_bf16(
                    af[mi], bfr[nj], acc[4 + mi][nj], 0, 0, 0);
        __builtin_amdgcn_s_setprio(0);
        __builtin_amdgcn_s_barrier();
        // ---------------- Ph3: (h1, ks1) ----------------
        if (kt < 15) {  // publish A(kt+1) rows 0-63/128-191 into dead buf; load rest
            wrA(AdN + lA0, x0a, x0b); wrA(AdN + lA2, x1a, x1b);
            ldA(spN + off1, ok1, x0a, x0b);
            ldA(spN + off3, ok3, x1a, x1b);
            __builtin_amdgcn_sched_barrier(0);
        }
#pragma unroll
        for (int mi = 0; mi < 4; ++mi)
            af[mi] = *(const bf16x8*)(bA + 4096 + mi * 1024 + sA1);
#pragma unroll
        for (int nj = 0; nj < 4; ++nj)
            bfr[nj] = *(const bf16x8*)(bB + nj * 1024 + sA1);
        asm volatile("s_waitcnt lgkmcnt(0)" ::: "memory");
        __builtin_amdgcn_s_barrier();
        __builtin_amdgcn_s_setprio(1);
#pragma unroll
        for (int mi = 0; mi < 4; ++mi)
#pragma unroll
            for (int nj = 0; nj < 4; ++nj)
                acc[4 + mi][nj] = __builtin_amdgcn_mfma_f32_16x16x32_bf16(
                    af[mi], bfr[nj], acc[4 + mi][nj], 0, 0, 0);
        __builtin_amdgcn_s_setprio(0);
        __builtin_amdgcn_s_barrier();
        // ---------------- Ph4: (h0, ks1) ----------------
        if (kt < 14) {  // restage B(kt+2) into current buf (B reads done at Ph3)
            const size_t gk = (size_t)(kt + 2) * 64;
            async16(pB0 + gk, lds + bufO + lB0); async16(pB1 + gk, lds + bufO + lB1);
            async16(pB2 + gk, lds + bufO + lB2); async16(pB3 + gk, lds + bufO + lB3);
        }
#pragma unroll
        for (int mi = 0; mi < 4; ++mi)
            af[mi] = *(const bf16x8*)(bA + mi * 1024 + sA1);
        __builtin_amdgcn_s_barrier();
        __builtin_amdgcn_s_setprio(1);
#pragma unroll
        for (int mi = 0; mi < 4; ++mi)
#pragma unroll
            for (int nj = 0; nj < 4; ++nj)
                acc[mi][nj] = __builtin_amdgcn_mfma_f32_16x16x32_bf16(
                    af[mi], bfr[nj], acc[mi][nj], 0, 0, 0);
        __builtin_amdgcn_s_setprio(0);
        __builtin_amdgcn_s_barrier();
    }

    // epilogue: C/D layout col = lane&15, row = q*4 + reg (m89/m91 verified)
    const size_t outHalf = (colTile >= 2) ? (size_t)NROWS * 512 : 0;
    const int cb = (colTile & 1) * 256 + wn * 64;
    if (aRow0 + 256 <= NROWS) {       // full tile: branchless stores
#pragma unroll
        for (int mi8 = 0; mi8 < 8; ++mi8) {
            int rbase = aRow0 + wm * 128 + mi8 * 16 + q * 4;
#pragma unroll
            for (int nj = 0; nj < 4; ++nj) {
                int col = cb + nj * 16 + r16;
#pragma unroll
                for (int r = 0; r < 4; ++r)
                    C[outHalf + (size_t)(rbase + r) * 512 + col] = acc[mi8][nj][r];
            }
        }
    } else {
#pragma unroll
        for (int mi8 = 0; mi8 < 8; ++mi8) {
            int rbase = aRow0 + wm * 128 + mi8 * 16 + q * 4;
#pragma unroll
            for (int nj = 0; nj < 4; ++nj) {
                int col = cb + nj * 16 + r16;
#pragma unroll
                for (int r = 0; r < 4; ++r) {
                    int row = rbase + r;
                    if (row < NROWS)
                        C[outHalf + (size_t)row * 512 + col] = acc[mi8][nj][r];
                }
            }
        }
    }
}

// ---------------- fp32 fallback (only if ws too small) ----------------
__global__ void fallback_kernel(const float* __restrict__ xre,
                                const float* __restrict__ xim,
                                const float* __restrict__ Re,
                                const float* __restrict__ Im,
                                float* __restrict__ out) {
    __shared__ float sre[512], sim[512];
    int n = blockIdx.x;
    for (int i = threadIdx.x; i < 512; i += 256) {
        sre[i] = xre[(size_t)n * 512 + i];
        sim[i] = xim[(size_t)n * 512 + i];
    }
    __syncthreads();
    for (int o = threadIdx.x; o < 512; o += 256) {
        float are = 0.f, aim = 0.f;
        for (int k = 0; k < 512; ++k) {
            float wr = Re[(size_t)o * 512 + k], wi = Im[(size_t)o * 512 + k];
            float xr = sre[k], xi = sim[k];
            are += xr * wr - xi * wi;
            aim += xr * wi + xi * wr;
        }
        out[(size_t)n * 512 + o] = are;
        out[(size_t)NROWS * 512 + (size_t)n * 512 + o] = aim;
    }
}

extern "C" void kernel_launch(void* const* d_in, const int* in_sizes, int n_in,
                              void* d_out, int out_size, void* d_ws, size_t ws_size,
                              hipStream_t stream) {
    const float* xre = (const float*)d_in[0];
    const float* xim = (const float*)d_in[1];
    const float* Re  = (const float*)d_in[2];
    const float* Im  = (const float*)d_in[3];
    float* out = (float*)d_out;

    const size_t bBytes = (size_t)1024 * KDIM * 2;   // 2 MiB packed weights
    if (ws_size >= bBytes) {
        uint16_t* Bt = (uint16_t*)d_ws;
        pack_b_kernel<<<(1024 * 128) / 256, 256, 0, stream>>>(Re, Im, Bt);
        gemm8<<<NBLK, 512, 0, stream>>>(xre, xim, Bt, out);
    } else {
        fallback_kernel<<<NROWS, 256, 0, stream>>>(xre, xim, Re, Im, out);
    }
}